// Round 1
// baseline (1005.335 us; speedup 1.0000x reference)
//
#include <hip/hip_runtime.h>
#include <hip/hip_bf16.h>

#define N_NODES 131072
#define N_EDGES 1048576
#define B_GR    128
#define NPG_    1024
#define KTOP    30

// ---------------- CSR build ----------------

__global__ __launch_bounds__(256) void k_zero(int* cnt) {
    int i = blockIdx.x * 256 + threadIdx.x;
    if (i < N_NODES) cnt[i] = 0;
}

__global__ __launch_bounds__(256) void k_count(const int* __restrict__ dst, int* __restrict__ cnt) {
    int e = blockIdx.x * 256 + threadIdx.x;
    if (e < N_EDGES) atomicAdd(&cnt[dst[e]], 1);
}

__global__ __launch_bounds__(256) void k_scan1(const int* __restrict__ cnt,
                                               int* __restrict__ row_start,
                                               int* __restrict__ blocksum) {
    __shared__ int s[256];
    int t = threadIdx.x;
    int i = blockIdx.x * 256 + t;
    int v = cnt[i];
    s[t] = v; __syncthreads();
    for (int o = 1; o < 256; o <<= 1) {
        int x = (t >= o) ? s[t - o] : 0;
        __syncthreads();
        s[t] += x;
        __syncthreads();
    }
    row_start[i] = s[t] - v;           // exclusive within chunk
    if (t == 255) blocksum[blockIdx.x] = s[t];
}

__global__ __launch_bounds__(512) void k_scan2(int* __restrict__ blocksum) {
    __shared__ int s[512];
    int t = threadIdx.x;
    int v = blocksum[t];
    s[t] = v; __syncthreads();
    for (int o = 1; o < 512; o <<= 1) {
        int x = (t >= o) ? s[t - o] : 0;
        __syncthreads();
        s[t] += x;
        __syncthreads();
    }
    blocksum[t] = s[t] - v;            // exclusive block offsets
}

__global__ __launch_bounds__(256) void k_scan3(int* __restrict__ row_start,
                                               const int* __restrict__ blocksum,
                                               int* __restrict__ cursor) {
    int i = blockIdx.x * 256 + threadIdx.x;
    int r = row_start[i] + blocksum[blockIdx.x];
    row_start[i] = r;
    cursor[i] = r;
}

__global__ __launch_bounds__(256) void k_fill(const int* __restrict__ src,
                                              const int* __restrict__ dst,
                                              int* __restrict__ cursor,
                                              int* __restrict__ csr_src,
                                              int* __restrict__ csr_eid) {
    int e = blockIdx.x * 256 + threadIdx.x;
    if (e < N_EDGES) {
        int d = dst[e];
        int pos = atomicAdd(&cursor[d], 1);
        csr_src[pos] = src[e];
        csr_eid[pos] = e;
    }
}

// ---------------- cur0 = [node_feat | e2n], deg ----------------

__global__ __launch_bounds__(256) void k_build(const float* __restrict__ node_feat,
                                               const float* __restrict__ edge_feat,
                                               const int* __restrict__ row_start,
                                               const int* __restrict__ cnt,
                                               const int* __restrict__ csr_eid,
                                               float* __restrict__ cur0,
                                               float* __restrict__ degf) {
    int wave = threadIdx.x >> 6, lane = threadIdx.x & 63;
    int n = blockIdx.x * 4 + wave;
    float* out = cur0 + (size_t)n * 160;
    const float* nf = node_feat + (size_t)n * 128;
    out[lane]      = nf[lane];
    out[64 + lane] = nf[64 + lane];
    int start = row_start[n], len = cnt[n];
    if (lane < 32) {
        float s = 0.f;
        for (int i = 0; i < len; ++i) {
            int e = csr_eid[start + i];
            s += edge_feat[(size_t)e * 32 + lane];
        }
        out[128 + lane] = s;
    }
    if (lane == 0) degf[n] = 1.0f + (float)len;
}

// ---------------- layer 0: 160 -> 32 ----------------

__global__ __launch_bounds__(256) void k_layer0(const float* __restrict__ cur0,
                                                const int* __restrict__ row_start,
                                                const int* __restrict__ cnt,
                                                const int* __restrict__ csr_src,
                                                const float* __restrict__ W0,
                                                const float* __restrict__ b0,
                                                const float* __restrict__ degf,
                                                float* __restrict__ h0,
                                                float* __restrict__ feat) {
    __shared__ float lds[4][160];
    int wave = threadIdx.x >> 6, lane = threadIdx.x & 63;
    int n = blockIdx.x * 4 + wave;
    const float* row = cur0 + (size_t)n * 160;
    float p0 = row[lane], p1 = row[64 + lane];
    float p2 = (lane < 32) ? row[128 + lane] : 0.f;
    int start = row_start[n], len = cnt[n];
    for (int i = 0; i < len; ++i) {
        const float* r = cur0 + (size_t)csr_src[start + i] * 160;
        p0 += r[lane];
        p1 += r[64 + lane];
        if (lane < 32) p2 += r[128 + lane];
    }
    lds[wave][lane] = p0;
    lds[wave][64 + lane] = p1;
    if (lane < 32) lds[wave][128 + lane] = p2;
    __syncthreads();
    int j = lane & 31, half = lane >> 5;
    float acc = 0.f;
    int f0 = half * 80;
    for (int f = f0; f < f0 + 80; ++f) acc += lds[wave][f] * W0[f * 32 + j];
    acc += __shfl_xor(acc, 32, 64);
    if (lane < 32) {
        float v = tanhf((acc + b0[j]) / degf[n]);
        h0[(size_t)n * 32 + j] = v;
        feat[(size_t)n * 97 + j] = v;
    }
}

// ---------------- layers 1,2: 32 -> 32 ----------------

__global__ __launch_bounds__(256) void k_layer_mid(const float* __restrict__ hin,
                                                   const int* __restrict__ row_start,
                                                   const int* __restrict__ cnt,
                                                   const int* __restrict__ csr_src,
                                                   const float* __restrict__ W,
                                                   const float* __restrict__ b,
                                                   const float* __restrict__ degf,
                                                   float* __restrict__ hout,
                                                   float* __restrict__ feat,
                                                   int coloff) {
    int half = threadIdx.x >> 5;
    int f = threadIdx.x & 31;
    int n = blockIdx.x * 8 + half;
    float p = hin[(size_t)n * 32 + f];
    int start = row_start[n], len = cnt[n];
    for (int i = 0; i < len; ++i) p += hin[(size_t)csr_src[start + i] * 32 + f];
    float acc = 0.f;
    for (int ff = 0; ff < 32; ++ff) acc += __shfl(p, ff, 32) * W[ff * 32 + f];
    float v = tanhf((acc + b[f]) / degf[n]);
    hout[(size_t)n * 32 + f] = v;
    feat[(size_t)n * 97 + coloff + f] = v;
}

// ---------------- layer 3: 32 -> 1 ----------------

__global__ __launch_bounds__(256) void k_layer3(const float* __restrict__ hin,
                                                const int* __restrict__ row_start,
                                                const int* __restrict__ cnt,
                                                const int* __restrict__ csr_src,
                                                const float* __restrict__ W3,
                                                const float* __restrict__ b3,
                                                const float* __restrict__ degf,
                                                float* __restrict__ feat) {
    int half = threadIdx.x >> 5, f = threadIdx.x & 31;
    int n = blockIdx.x * 8 + half;
    float p = hin[(size_t)n * 32 + f];
    int start = row_start[n], len = cnt[n];
    for (int i = 0; i < len; ++i) p += hin[(size_t)csr_src[start + i] * 32 + f];
    float t = p * W3[f];
    for (int m = 16; m > 0; m >>= 1) t += __shfl_xor(t, m, 32);
    if (f == 0) feat[(size_t)n * 97 + 96] = tanhf((t + b3[0]) / degf[n]);
}

// ---------------- top-k + conv head, one block per graph ----------------

__device__ inline unsigned long long packkey(float v, int u) {
    unsigned int bbits = __float_as_uint(v);
    unsigned int ord = (bbits & 0x80000000u) ? ~bbits : (bbits | 0x80000000u);
    return ((unsigned long long)ord << 32) | (unsigned int)(0xFFFFFFFFu - (unsigned int)u);
}

__global__ __launch_bounds__(256) void k_head(const float* __restrict__ feat,
                                              const float* __restrict__ wc1,
                                              const float* __restrict__ bc1,
                                              const float* __restrict__ wc2,
                                              const float* __restrict__ bc2,
                                              const float* __restrict__ wout,
                                              const float* __restrict__ bout,
                                              float* __restrict__ out) {
    __shared__ float vals[1024];
    __shared__ unsigned long long keys[256];
    __shared__ int selidx[KTOP];
    __shared__ float sp[KTOP * 97];
    __shared__ float y1[16 * 30];
    __shared__ float pool[16 * 15];
    __shared__ float y2[352];
    int b = blockIdx.x, tid = threadIdx.x;
    const float* fb = feat + (size_t)b * NPG_ * 97;
    for (int u = tid; u < NPG_; u += 256) vals[u] = fb[(size_t)u * 97 + 96];
    __syncthreads();
    // iterative top-30 selection: max value, tie -> lowest index (JAX top_k order)
    for (int k = 0; k < KTOP; ++k) {
        unsigned long long bk = 0;
        for (int u = tid; u < NPG_; u += 256) {
            unsigned long long kk = packkey(vals[u], u);
            if (kk > bk) bk = kk;
        }
        keys[tid] = bk; __syncthreads();
        for (int s = 128; s > 0; s >>= 1) {
            if (tid < s) {
                if (keys[tid + s] > keys[tid]) keys[tid] = keys[tid + s];
            }
            __syncthreads();
        }
        if (tid == 0) {
            int u = (int)(0xFFFFFFFFu - (unsigned int)(keys[0] & 0xFFFFFFFFull));
            selidx[k] = u;
            vals[u] = -1e30f;
        }
        __syncthreads();
    }
    // gather sorted rows
    for (int idx = tid; idx < KTOP * 97; idx += 256) {
        int t = idx / 97, d = idx - t * 97;
        sp[idx] = fb[(size_t)selidx[t] * 97 + d];
    }
    __syncthreads();
    // conv1: kernel=97 stride=97 -> per selected node linear 97->16, relu
    for (int idx = tid; idx < 480; idx += 256) {
        int t = idx >> 4, c = idx & 15;
        float acc = bc1[c];
        for (int d = 0; d < 97; ++d) acc += sp[t * 97 + d] * wc1[c * 97 + d];
        y1[c * 30 + t] = fmaxf(acc, 0.f);
    }
    __syncthreads();
    // maxpool(2,2)
    for (int idx = tid; idx < 240; idx += 256) {
        int c = idx / 15, u = idx - c * 15;
        pool[c * 15 + u] = fmaxf(y1[c * 30 + 2 * u], y1[c * 30 + 2 * u + 1]);
    }
    __syncthreads();
    // conv2: 16->32, kernel 5, relu
    for (int idx = tid; idx < 352; idx += 256) {
        int o = idx / 11, t = idx - o * 11;
        float acc = bc2[o];
        for (int i = 0; i < 16; ++i)
            for (int kk = 0; kk < 5; ++kk)
                acc += pool[i * 15 + t + kk] * wc2[(o * 16 + i) * 5 + kk];
        y2[idx] = fmaxf(acc, 0.f);
    }
    __syncthreads();
    // dense 352 -> 2, relu
    if (tid < 2) {
        float acc = bout[tid];
        for (int m = 0; m < 352; ++m) acc += y2[m] * wout[m * 2 + tid];
        out[b * 2 + tid] = fmaxf(acc, 0.f);
    }
}

// ---------------- launch ----------------

extern "C" void kernel_launch(void* const* d_in, const int* in_sizes, int n_in,
                              void* d_out, int out_size, void* d_ws, size_t ws_size,
                              hipStream_t stream) {
    const float* node_feat = (const float*)d_in[0];
    const float* edge_feat = (const float*)d_in[1];
    const int*   eidx      = (const int*)d_in[2];
    const float* W0 = (const float*)d_in[3];
    const float* b0 = (const float*)d_in[4];
    const float* W1 = (const float*)d_in[5];
    const float* b1 = (const float*)d_in[6];
    const float* W2 = (const float*)d_in[7];
    const float* b2 = (const float*)d_in[8];
    const float* W3 = (const float*)d_in[9];
    const float* b3 = (const float*)d_in[10];
    const float* wc1 = (const float*)d_in[11];
    const float* bc1 = (const float*)d_in[12];
    const float* wc2 = (const float*)d_in[13];
    const float* bc2 = (const float*)d_in[14];
    const float* wout = (const float*)d_in[15];
    const float* bout = (const float*)d_in[16];
    float* out = (float*)d_out;

    const int* src = eidx;
    const int* dst = eidx + N_EDGES;

    char* ws = (char*)d_ws;
    size_t off = 0;
    auto alloc = [&](size_t bytes) -> char* {
        char* p = ws + off;
        off += (bytes + 255) & ~(size_t)255;
        return p;
    };
    int* cnt       = (int*)alloc((size_t)N_NODES * 4);
    int* row_start = (int*)alloc((size_t)N_NODES * 4);
    int* cursor    = (int*)alloc((size_t)N_NODES * 4);
    int* blocksum  = (int*)alloc(512 * 4);
    float* degf    = (float*)alloc((size_t)N_NODES * 4);
    int* csr_src   = (int*)alloc((size_t)N_EDGES * 4);
    int* csr_eid   = (int*)alloc((size_t)N_EDGES * 4);
    float* cur0    = (float*)alloc((size_t)N_NODES * 160 * 4);
    float* h_a     = (float*)alloc((size_t)N_NODES * 32 * 4);
    float* h_b     = (float*)alloc((size_t)N_NODES * 32 * 4);
    float* feat    = (float*)alloc((size_t)N_NODES * 97 * 4);
    (void)ws_size;

    k_zero<<<N_NODES / 256, 256, 0, stream>>>(cnt);
    k_count<<<N_EDGES / 256, 256, 0, stream>>>(dst, cnt);
    k_scan1<<<N_NODES / 256, 256, 0, stream>>>(cnt, row_start, blocksum);
    k_scan2<<<1, 512, 0, stream>>>(blocksum);
    k_scan3<<<N_NODES / 256, 256, 0, stream>>>(row_start, blocksum, cursor);
    k_fill<<<N_EDGES / 256, 256, 0, stream>>>(src, dst, cursor, csr_src, csr_eid);
    k_build<<<N_NODES / 4, 256, 0, stream>>>(node_feat, edge_feat, row_start, cnt, csr_eid, cur0, degf);
    k_layer0<<<N_NODES / 4, 256, 0, stream>>>(cur0, row_start, cnt, csr_src, W0, b0, degf, h_a, feat);
    k_layer_mid<<<N_NODES / 8, 256, 0, stream>>>(h_a, row_start, cnt, csr_src, W1, b1, degf, h_b, feat, 32);
    k_layer_mid<<<N_NODES / 8, 256, 0, stream>>>(h_b, row_start, cnt, csr_src, W2, b2, degf, h_a, feat, 64);
    k_layer3<<<N_NODES / 8, 256, 0, stream>>>(h_a, row_start, cnt, csr_src, W3, b3, degf, feat);
    k_head<<<B_GR, 256, 0, stream>>>(feat, wc1, bc1, wc2, bc2, wout, bout, out);
}

// Round 2
// 892.431 us; speedup vs baseline: 1.1265x; 1.1265x over previous
//
#include <hip/hip_runtime.h>
#include <hip/hip_bf16.h>
#include <math.h>

#define N_NODES 131072
#define N_EDGES 1048576
#define B_GR    128
#define NPG_    1024
#define KTOP    30

// ---------------- CSR build ----------------

__global__ __launch_bounds__(256) void k_zero(int* cnt) {
    int i = blockIdx.x * 256 + threadIdx.x;
    if (i < N_NODES) cnt[i] = 0;
}

__global__ __launch_bounds__(256) void k_count(const int* __restrict__ dst, int* __restrict__ cnt) {
    int e = blockIdx.x * 256 + threadIdx.x;
    if (e < N_EDGES) atomicAdd(&cnt[dst[e]], 1);
}

__global__ __launch_bounds__(256) void k_scan1(const int* __restrict__ cnt,
                                               int* __restrict__ row_start,
                                               int* __restrict__ blocksum) {
    __shared__ int s[256];
    int t = threadIdx.x;
    int i = blockIdx.x * 256 + t;
    int v = cnt[i];
    s[t] = v; __syncthreads();
    for (int o = 1; o < 256; o <<= 1) {
        int x = (t >= o) ? s[t - o] : 0;
        __syncthreads();
        s[t] += x;
        __syncthreads();
    }
    row_start[i] = s[t] - v;
    if (t == 255) blocksum[blockIdx.x] = s[t];
}

__global__ __launch_bounds__(512) void k_scan2(int* __restrict__ blocksum) {
    __shared__ int s[512];
    int t = threadIdx.x;
    int v = blocksum[t];
    s[t] = v; __syncthreads();
    for (int o = 1; o < 512; o <<= 1) {
        int x = (t >= o) ? s[t - o] : 0;
        __syncthreads();
        s[t] += x;
        __syncthreads();
    }
    blocksum[t] = s[t] - v;
}

__global__ __launch_bounds__(256) void k_scan3(int* __restrict__ row_start,
                                               const int* __restrict__ blocksum,
                                               int* __restrict__ cursor) {
    int i = blockIdx.x * 256 + threadIdx.x;
    int r = row_start[i] + blocksum[blockIdx.x];
    row_start[i] = r;
    cursor[i] = r;
}

__global__ __launch_bounds__(256) void k_fill(const int* __restrict__ src,
                                              const int* __restrict__ dst,
                                              int* __restrict__ cursor,
                                              int* __restrict__ csr_src,
                                              int* __restrict__ edge_pos) {
    int e = blockIdx.x * 256 + threadIdx.x;
    if (e < N_EDGES) {
        int d = dst[e];
        int pos = atomicAdd(&cursor[d], 1);
        csr_src[pos] = src[e];
        edge_pos[e] = pos;
    }
}

// ---------------- ze[pos(e)] = edge_feat[e] @ W0[128:160,:]  (scatter into CSR order)

__global__ __launch_bounds__(256) void k_edge_gemm(const float* __restrict__ ef,
                                                   const float* __restrict__ W0,
                                                   const int* __restrict__ edge_pos,
                                                   float* __restrict__ ze) {
    __shared__ float w[32 * 32];
    int tid = threadIdx.x;
    for (int i = tid; i < 1024; i += 256) w[i] = W0[128 * 32 + i];
    __syncthreads();
    int g = tid >> 5, j = tid & 31;
    for (int base = blockIdx.x; base < N_EDGES / 8; base += 8192) {
        int e = base * 8 + g;
        float v = ef[(size_t)e * 32 + j];
        float acc = 0.f;
        #pragma unroll
        for (int k = 0; k < 32; ++k)
            acc += __shfl(v, k, 32) * w[k * 32 + j];
        int pos = edge_pos[e];
        ze[(size_t)pos * 32 + j] = acc;
    }
}

// ---------------- z0[n] = node_feat[n] @ W0[0:128,:] + sum(ze rows); degf

__global__ __launch_bounds__(256) void k_z(const float* __restrict__ nf,
                                           const float* __restrict__ W0,
                                           const int* __restrict__ row_start,
                                           const int* __restrict__ cnt,
                                           const float* __restrict__ ze,
                                           float* __restrict__ z0,
                                           float* __restrict__ degf) {
    __shared__ float w[128 * 32];
    int tid = threadIdx.x;
    for (int i = tid; i < 4096; i += 256) w[i] = W0[i];
    __syncthreads();
    int g = tid >> 5, j = tid & 31;
    for (int base = blockIdx.x; base < N_NODES / 8; base += 4096) {
        int n = base * 8 + g;
        const float* nfr = nf + (size_t)n * 128;
        float acc = 0.f;
        #pragma unroll
        for (int c = 0; c < 4; ++c) {
            float v = nfr[c * 32 + j];
            #pragma unroll
            for (int k = 0; k < 32; ++k)
                acc += __shfl(v, k, 32) * w[(c * 32 + k) * 32 + j];
        }
        int start = row_start[n], len = cnt[n];
        const float* zr = ze + (size_t)start * 32;
        int i = 0;
        for (; i + 4 <= len; i += 4)
            acc += zr[i * 32 + j] + zr[(i + 1) * 32 + j] + zr[(i + 2) * 32 + j] + zr[(i + 3) * 32 + j];
        for (; i < len; ++i) acc += zr[i * 32 + j];
        z0[(size_t)n * 32 + j] = acc;
        if (j == 0) degf[n] = 1.f + (float)len;
    }
}

// ---------------- gather layer (used for layers 0,1): h = tanh((z_self+sum z_nb + b)/deg);
//                  writes feat col block; premultiplies z_next = h @ Wnext

__global__ __launch_bounds__(256) void k_gather(const float* __restrict__ zin,
                                                const int* __restrict__ row_start,
                                                const int* __restrict__ cnt,
                                                const int* __restrict__ csr_src,
                                                const float* __restrict__ bias,
                                                const float* __restrict__ degf,
                                                const float* __restrict__ Wnext,
                                                float* __restrict__ feat, int coloff,
                                                float* __restrict__ zout) {
    __shared__ float w[1024];
    int tid = threadIdx.x;
    for (int i = tid; i < 1024; i += 256) w[i] = Wnext[i];
    __syncthreads();
    int g = tid >> 5, j = tid & 31;
    int n = blockIdx.x * 8 + g;
    int start = row_start[n], len = cnt[n];
    const int* cs = csr_src + start;
    float p = zin[(size_t)n * 32 + j];
    int i = 0;
    for (; i + 4 <= len; i += 4) {
        int s0 = cs[i], s1 = cs[i + 1], s2 = cs[i + 2], s3 = cs[i + 3];
        p += zin[(size_t)s0 * 32 + j];
        p += zin[(size_t)s1 * 32 + j];
        p += zin[(size_t)s2 * 32 + j];
        p += zin[(size_t)s3 * 32 + j];
    }
    for (; i < len; ++i) p += zin[(size_t)cs[i] * 32 + j];
    float h = tanhf((p + bias[j]) / degf[n]);
    feat[(size_t)n * 97 + coloff + j] = h;
    float acc = 0.f;
    #pragma unroll
    for (int k = 0; k < 32; ++k)
        acc += __shfl(h, k, 32) * w[k * 32 + j];
    zout[(size_t)n * 32 + j] = acc;
}

// ---------------- layer 2: premultiply against W3 (32->1) into scalar z3

__global__ __launch_bounds__(256) void k_gather2(const float* __restrict__ zin,
                                                 const int* __restrict__ row_start,
                                                 const int* __restrict__ cnt,
                                                 const int* __restrict__ csr_src,
                                                 const float* __restrict__ bias,
                                                 const float* __restrict__ degf,
                                                 const float* __restrict__ W3,
                                                 float* __restrict__ feat,
                                                 float* __restrict__ z3) {
    int tid = threadIdx.x;
    int g = tid >> 5, j = tid & 31;
    int n = blockIdx.x * 8 + g;
    int start = row_start[n], len = cnt[n];
    const int* cs = csr_src + start;
    float p = zin[(size_t)n * 32 + j];
    int i = 0;
    for (; i + 4 <= len; i += 4) {
        int s0 = cs[i], s1 = cs[i + 1], s2 = cs[i + 2], s3 = cs[i + 3];
        p += zin[(size_t)s0 * 32 + j];
        p += zin[(size_t)s1 * 32 + j];
        p += zin[(size_t)s2 * 32 + j];
        p += zin[(size_t)s3 * 32 + j];
    }
    for (; i < len; ++i) p += zin[(size_t)cs[i] * 32 + j];
    float h = tanhf((p + bias[j]) / degf[n]);
    feat[(size_t)n * 97 + 64 + j] = h;
    float t = h * W3[j];
    #pragma unroll
    for (int o = 16; o; o >>= 1) t += __shfl_xor(t, o, 32);
    if (j == 0) z3[n] = t;
}

// ---------------- layer 3: scalar gather-sum

__global__ __launch_bounds__(256) void k_gather3(const float* __restrict__ z3,
                                                 const int* __restrict__ row_start,
                                                 const int* __restrict__ cnt,
                                                 const int* __restrict__ csr_src,
                                                 const float* __restrict__ b3,
                                                 const float* __restrict__ degf,
                                                 float* __restrict__ feat) {
    int n = blockIdx.x * 256 + threadIdx.x;
    int start = row_start[n], len = cnt[n];
    const int* cs = csr_src + start;
    float s = z3[n];
    int i = 0;
    for (; i + 4 <= len; i += 4)
        s += z3[cs[i]] + z3[cs[i + 1]] + z3[cs[i + 2]] + z3[cs[i + 3]];
    for (; i < len; ++i) s += z3[cs[i]];
    feat[(size_t)n * 97 + 96] = tanhf((s + b3[0]) / degf[n]);
}

// ---------------- top-k + conv head, one block per graph ----------------

__global__ __launch_bounds__(256) void k_head(const float* __restrict__ feat,
                                              const float* __restrict__ wc1,
                                              const float* __restrict__ bc1,
                                              const float* __restrict__ wc2,
                                              const float* __restrict__ bc2,
                                              const float* __restrict__ wout,
                                              const float* __restrict__ bout,
                                              float* __restrict__ out) {
    __shared__ float vals[1024];
    __shared__ int selidx[KTOP];
    __shared__ float sp[KTOP * 97];
    __shared__ float y1[16 * 30];
    __shared__ float pool[16 * 15];
    __shared__ float y2[352];
    int b = blockIdx.x, tid = threadIdx.x;
    const float* fb = feat + (size_t)b * NPG_ * 97;
    for (int u = tid; u < NPG_; u += 256) vals[u] = fb[(size_t)u * 97 + 96];
    __syncthreads();
    // single-wave register tournament: max value, tie -> lowest index (JAX top_k order)
    if (tid < 64) {
        unsigned long long keys[16];
        #pragma unroll
        for (int r = 0; r < 16; ++r) {
            int u = tid * 16 + r;
            unsigned int bb = __float_as_uint(vals[u]);
            unsigned int ord = (bb & 0x80000000u) ? ~bb : (bb | 0x80000000u);
            keys[r] = ((unsigned long long)ord << 32) |
                      (unsigned long long)(0xFFFFFFFFu - (unsigned int)u);
        }
        for (int k = 0; k < KTOP; ++k) {
            unsigned long long m = keys[0];
            #pragma unroll
            for (int r = 1; r < 16; ++r) m = (keys[r] > m) ? keys[r] : m;
            #pragma unroll
            for (int o = 32; o; o >>= 1) {
                unsigned long long t = __shfl_xor(m, o);
                m = (t > m) ? t : m;
            }
            int u = (int)(0xFFFFFFFFu - (unsigned int)(m & 0xFFFFFFFFull));
            if (tid == 0) selidx[k] = u;
            #pragma unroll
            for (int r = 0; r < 16; ++r)
                if (tid * 16 + r == u) keys[r] = 0ull;
        }
    }
    __syncthreads();
    for (int idx = tid; idx < KTOP * 97; idx += 256) {
        int t = idx / 97, d = idx - t * 97;
        sp[idx] = fb[(size_t)selidx[t] * 97 + d];
    }
    __syncthreads();
    for (int idx = tid; idx < 480; idx += 256) {
        int t = idx >> 4, c = idx & 15;
        float acc = bc1[c];
        for (int d = 0; d < 97; ++d) acc += sp[t * 97 + d] * wc1[c * 97 + d];
        y1[c * 30 + t] = fmaxf(acc, 0.f);
    }
    __syncthreads();
    for (int idx = tid; idx < 240; idx += 256) {
        int c = idx / 15, u = idx - c * 15;
        pool[c * 15 + u] = fmaxf(y1[c * 30 + 2 * u], y1[c * 30 + 2 * u + 1]);
    }
    __syncthreads();
    for (int idx = tid; idx < 352; idx += 256) {
        int o = idx / 11, t = idx - o * 11;
        float acc = bc2[o];
        for (int i = 0; i < 16; ++i)
            for (int kk = 0; kk < 5; ++kk)
                acc += pool[i * 15 + t + kk] * wc2[(o * 16 + i) * 5 + kk];
        y2[idx] = fmaxf(acc, 0.f);
    }
    __syncthreads();
    if (tid < 2) {
        float acc = bout[tid];
        for (int m = 0; m < 352; ++m) acc += y2[m] * wout[m * 2 + tid];
        out[b * 2 + tid] = fmaxf(acc, 0.f);
    }
}

// ---------------- launch ----------------

extern "C" void kernel_launch(void* const* d_in, const int* in_sizes, int n_in,
                              void* d_out, int out_size, void* d_ws, size_t ws_size,
                              hipStream_t stream) {
    const float* node_feat = (const float*)d_in[0];
    const float* edge_feat = (const float*)d_in[1];
    const int*   eidx      = (const int*)d_in[2];
    const float* W0 = (const float*)d_in[3];
    const float* b0 = (const float*)d_in[4];
    const float* W1 = (const float*)d_in[5];
    const float* b1 = (const float*)d_in[6];
    const float* W2 = (const float*)d_in[7];
    const float* b2 = (const float*)d_in[8];
    const float* W3 = (const float*)d_in[9];
    const float* b3 = (const float*)d_in[10];
    const float* wc1 = (const float*)d_in[11];
    const float* bc1 = (const float*)d_in[12];
    const float* wc2 = (const float*)d_in[13];
    const float* bc2 = (const float*)d_in[14];
    const float* wout = (const float*)d_in[15];
    const float* bout = (const float*)d_in[16];
    float* out = (float*)d_out;

    const int* src = eidx;
    const int* dst = eidx + N_EDGES;

    char* ws = (char*)d_ws;
    size_t off = 0;
    auto alloc = [&](size_t bytes) -> char* {
        char* p = ws + off;
        off += (bytes + 255) & ~(size_t)255;
        return p;
    };
    int* cnt       = (int*)alloc((size_t)N_NODES * 4);
    int* row_start = (int*)alloc((size_t)N_NODES * 4);
    int* cursor    = (int*)alloc((size_t)N_NODES * 4);
    int* blocksum  = (int*)alloc(512 * 4);
    float* degf    = (float*)alloc((size_t)N_NODES * 4);
    int* csr_src   = (int*)alloc((size_t)N_EDGES * 4);
    int* edge_pos  = (int*)alloc((size_t)N_EDGES * 4);
    float* z0      = (float*)alloc((size_t)N_NODES * 32 * 4);
    // big region: ze (128 MB) lives only until k_z completes; feat/z1/z2/z3 are
    // written strictly after, so they alias the same region.
    char* region   = alloc((size_t)N_EDGES * 32 * 4);
    float* ze   = (float*)region;
    float* feat = (float*)region;                                   // N*97*4 = 50,855,936
    float* z1   = (float*)(region + 50856192);                      // 16 MB
    float* z2   = (float*)(region + 50856192 + 16777216);           // 16 MB
    float* z3   = (float*)(region + 50856192 + 33554432);           // 512 KB
    (void)ws_size;

    k_zero<<<N_NODES / 256, 256, 0, stream>>>(cnt);
    k_count<<<N_EDGES / 256, 256, 0, stream>>>(dst, cnt);
    k_scan1<<<N_NODES / 256, 256, 0, stream>>>(cnt, row_start, blocksum);
    k_scan2<<<1, 512, 0, stream>>>(blocksum);
    k_scan3<<<N_NODES / 256, 256, 0, stream>>>(row_start, blocksum, cursor);
    k_fill<<<N_EDGES / 256, 256, 0, stream>>>(src, dst, cursor, csr_src, edge_pos);
    k_edge_gemm<<<8192, 256, 0, stream>>>(edge_feat, W0, edge_pos, ze);
    k_z<<<4096, 256, 0, stream>>>(node_feat, W0, row_start, cnt, ze, z0, degf);
    k_gather<<<N_NODES / 8, 256, 0, stream>>>(z0, row_start, cnt, csr_src, b0, degf, W1, feat, 0, z1);
    k_gather<<<N_NODES / 8, 256, 0, stream>>>(z1, row_start, cnt, csr_src, b1, degf, W2, feat, 32, z2);
    k_gather2<<<N_NODES / 8, 256, 0, stream>>>(z2, row_start, cnt, csr_src, b2, degf, W3, feat, z3);
    k_gather3<<<N_NODES / 256, 256, 0, stream>>>(z3, row_start, cnt, csr_src, b3, degf, feat);
    k_head<<<B_GR, 256, 0, stream>>>(feat, wc1, bc1, wc2, bc2, wout, bout, out);
}

// Round 3
// 738.424 us; speedup vs baseline: 1.3615x; 1.2086x over previous
//
#include <hip/hip_runtime.h>
#include <hip/hip_bf16.h>
#include <math.h>

#define N_NODES 131072
#define N_EDGES 1048576
#define B_GR    128
#define NPG_    1024
#define KTOP    30

// ---------------- CSR build ----------------

__global__ __launch_bounds__(256) void k_zero(int* cnt) {
    int i = blockIdx.x * 256 + threadIdx.x;
    if (i < N_NODES) cnt[i] = 0;
}

__global__ __launch_bounds__(256) void k_count(const int* __restrict__ dst, int* __restrict__ cnt) {
    int e = blockIdx.x * 256 + threadIdx.x;
    if (e < N_EDGES) atomicAdd(&cnt[dst[e]], 1);
}

__global__ __launch_bounds__(256) void k_scan1(const int* __restrict__ cnt,
                                               int* __restrict__ row_start,
                                               int* __restrict__ blocksum) {
    __shared__ int s[256];
    int t = threadIdx.x;
    int i = blockIdx.x * 256 + t;
    int v = cnt[i];
    s[t] = v; __syncthreads();
    for (int o = 1; o < 256; o <<= 1) {
        int x = (t >= o) ? s[t - o] : 0;
        __syncthreads();
        s[t] += x;
        __syncthreads();
    }
    row_start[i] = s[t] - v;
    if (t == 255) blocksum[blockIdx.x] = s[t];
}

__global__ __launch_bounds__(512) void k_scan2(int* __restrict__ blocksum) {
    __shared__ int s[512];
    int t = threadIdx.x;
    int v = blocksum[t];
    s[t] = v; __syncthreads();
    for (int o = 1; o < 512; o <<= 1) {
        int x = (t >= o) ? s[t - o] : 0;
        __syncthreads();
        s[t] += x;
        __syncthreads();
    }
    blocksum[t] = s[t] - v;
}

__global__ __launch_bounds__(256) void k_scan3(int* __restrict__ row_start,
                                               const int* __restrict__ blocksum,
                                               int* __restrict__ cursor) {
    int i = blockIdx.x * 256 + threadIdx.x;
    int r = row_start[i] + blocksum[blockIdx.x];
    row_start[i] = r;
    cursor[i] = r;
}

__global__ __launch_bounds__(256) void k_fill(const int* __restrict__ src,
                                              const int* __restrict__ dst,
                                              int* __restrict__ cursor,
                                              int* __restrict__ csr_src,
                                              int* __restrict__ csr_eid) {
    int e = blockIdx.x * 256 + threadIdx.x;
    if (e < N_EDGES) {
        int d = dst[e];
        int pos = atomicAdd(&cursor[d], 1);
        csr_src[pos] = src[e];
        csr_eid[pos] = e;
    }
}

// ---------------- z0[n] = nf[n] @ W0[0:128,:] + (sum of incident ef rows) @ W0[128:160,:]

__global__ __launch_bounds__(256) void k_z(const float* __restrict__ nf,
                                           const float* __restrict__ ef,
                                           const float* __restrict__ W0,
                                           const int* __restrict__ row_start,
                                           const int* __restrict__ cnt,
                                           const int* __restrict__ csr_eid,
                                           float* __restrict__ z0,
                                           float* __restrict__ degf) {
    __shared__ float wa[128 * 32];
    __shared__ float wb[32 * 32];
    int tid = threadIdx.x;
    for (int i = tid; i < 4096; i += 256) wa[i] = W0[i];
    for (int i = tid; i < 1024; i += 256) wb[i] = W0[4096 + i];
    __syncthreads();
    int g = tid >> 5, j = tid & 31;
    int n = blockIdx.x * 8 + g;
    int start = row_start[n], len = cnt[n];
    const int* ce = csr_eid + start;
    // gather-sum incident edge features (each row = contiguous 128 B)
    float esum = 0.f;
    int i = 0;
    for (; i + 8 <= len; i += 8) {
        int e0 = ce[i], e1 = ce[i + 1], e2 = ce[i + 2], e3 = ce[i + 3];
        int e4 = ce[i + 4], e5 = ce[i + 5], e6 = ce[i + 6], e7 = ce[i + 7];
        float a0 = ef[(size_t)e0 * 32 + j], a1 = ef[(size_t)e1 * 32 + j];
        float a2 = ef[(size_t)e2 * 32 + j], a3 = ef[(size_t)e3 * 32 + j];
        float a4 = ef[(size_t)e4 * 32 + j], a5 = ef[(size_t)e5 * 32 + j];
        float a6 = ef[(size_t)e6 * 32 + j], a7 = ef[(size_t)e7 * 32 + j];
        esum += ((a0 + a1) + (a2 + a3)) + ((a4 + a5) + (a6 + a7));
    }
    for (; i < len; ++i) esum += ef[(size_t)ce[i] * 32 + j];
    // fused matmul
    const float* nfr = nf + (size_t)n * 128;
    float acc = 0.f;
    #pragma unroll
    for (int c = 0; c < 4; ++c) {
        float v = nfr[c * 32 + j];
        #pragma unroll
        for (int k = 0; k < 32; ++k)
            acc += __shfl(v, k, 32) * wa[(c * 32 + k) * 32 + j];
    }
    #pragma unroll
    for (int k = 0; k < 32; ++k)
        acc += __shfl(esum, k, 32) * wb[k * 32 + j];
    z0[(size_t)n * 32 + j] = acc;
    if (j == 0) degf[n] = 1.f + (float)len;
}

// ---------------- gather layer (layers 0,1): h = tanh((z_self+sum z_nb + b)/deg);
//                  writes feat col block; premultiplies z_next = h @ Wnext

__global__ __launch_bounds__(256) void k_gather(const float* __restrict__ zin,
                                                const int* __restrict__ row_start,
                                                const int* __restrict__ cnt,
                                                const int* __restrict__ csr_src,
                                                const float* __restrict__ bias,
                                                const float* __restrict__ degf,
                                                const float* __restrict__ Wnext,
                                                float* __restrict__ feat, int coloff,
                                                float* __restrict__ zout) {
    __shared__ float w[1024];
    int tid = threadIdx.x;
    for (int i = tid; i < 1024; i += 256) w[i] = Wnext[i];
    __syncthreads();
    int g = tid >> 5, j = tid & 31;
    int n = blockIdx.x * 8 + g;
    int start = row_start[n], len = cnt[n];
    const int* cs = csr_src + start;
    float p = zin[(size_t)n * 32 + j];
    int i = 0;
    for (; i + 8 <= len; i += 8) {
        int s0 = cs[i], s1 = cs[i + 1], s2 = cs[i + 2], s3 = cs[i + 3];
        int s4 = cs[i + 4], s5 = cs[i + 5], s6 = cs[i + 6], s7 = cs[i + 7];
        float a0 = zin[(size_t)s0 * 32 + j], a1 = zin[(size_t)s1 * 32 + j];
        float a2 = zin[(size_t)s2 * 32 + j], a3 = zin[(size_t)s3 * 32 + j];
        float a4 = zin[(size_t)s4 * 32 + j], a5 = zin[(size_t)s5 * 32 + j];
        float a6 = zin[(size_t)s6 * 32 + j], a7 = zin[(size_t)s7 * 32 + j];
        p += ((a0 + a1) + (a2 + a3)) + ((a4 + a5) + (a6 + a7));
    }
    for (; i < len; ++i) p += zin[(size_t)cs[i] * 32 + j];
    float h = tanhf((p + bias[j]) / degf[n]);
    feat[(size_t)n * 97 + coloff + j] = h;
    float acc = 0.f;
    #pragma unroll
    for (int k = 0; k < 32; ++k)
        acc += __shfl(h, k, 32) * w[k * 32 + j];
    zout[(size_t)n * 32 + j] = acc;
}

// ---------------- layer 2: premultiply against W3 (32->1) into scalar z3

__global__ __launch_bounds__(256) void k_gather2(const float* __restrict__ zin,
                                                 const int* __restrict__ row_start,
                                                 const int* __restrict__ cnt,
                                                 const int* __restrict__ csr_src,
                                                 const float* __restrict__ bias,
                                                 const float* __restrict__ degf,
                                                 const float* __restrict__ W3,
                                                 float* __restrict__ feat,
                                                 float* __restrict__ z3) {
    int tid = threadIdx.x;
    int g = tid >> 5, j = tid & 31;
    int n = blockIdx.x * 8 + g;
    int start = row_start[n], len = cnt[n];
    const int* cs = csr_src + start;
    float p = zin[(size_t)n * 32 + j];
    int i = 0;
    for (; i + 8 <= len; i += 8) {
        int s0 = cs[i], s1 = cs[i + 1], s2 = cs[i + 2], s3 = cs[i + 3];
        int s4 = cs[i + 4], s5 = cs[i + 5], s6 = cs[i + 6], s7 = cs[i + 7];
        float a0 = zin[(size_t)s0 * 32 + j], a1 = zin[(size_t)s1 * 32 + j];
        float a2 = zin[(size_t)s2 * 32 + j], a3 = zin[(size_t)s3 * 32 + j];
        float a4 = zin[(size_t)s4 * 32 + j], a5 = zin[(size_t)s5 * 32 + j];
        float a6 = zin[(size_t)s6 * 32 + j], a7 = zin[(size_t)s7 * 32 + j];
        p += ((a0 + a1) + (a2 + a3)) + ((a4 + a5) + (a6 + a7));
    }
    for (; i < len; ++i) p += zin[(size_t)cs[i] * 32 + j];
    float h = tanhf((p + bias[j]) / degf[n]);
    feat[(size_t)n * 97 + 64 + j] = h;
    float t = h * W3[j];
    #pragma unroll
    for (int o = 16; o; o >>= 1) t += __shfl_xor(t, o, 32);
    if (j == 0) z3[n] = t;
}

// ---------------- layer 3: scalar gather-sum

__global__ __launch_bounds__(256) void k_gather3(const float* __restrict__ z3,
                                                 const int* __restrict__ row_start,
                                                 const int* __restrict__ cnt,
                                                 const int* __restrict__ csr_src,
                                                 const float* __restrict__ b3,
                                                 const float* __restrict__ degf,
                                                 float* __restrict__ feat) {
    int n = blockIdx.x * 256 + threadIdx.x;
    int start = row_start[n], len = cnt[n];
    const int* cs = csr_src + start;
    float s = z3[n];
    int i = 0;
    for (; i + 4 <= len; i += 4)
        s += z3[cs[i]] + z3[cs[i + 1]] + z3[cs[i + 2]] + z3[cs[i + 3]];
    for (; i < len; ++i) s += z3[cs[i]];
    feat[(size_t)n * 97 + 96] = tanhf((s + b3[0]) / degf[n]);
}

// ---------------- top-k + conv head, one block per graph ----------------

__global__ __launch_bounds__(256) void k_head(const float* __restrict__ feat,
                                              const float* __restrict__ wc1,
                                              const float* __restrict__ bc1,
                                              const float* __restrict__ wc2,
                                              const float* __restrict__ bc2,
                                              const float* __restrict__ wout,
                                              const float* __restrict__ bout,
                                              float* __restrict__ out) {
    __shared__ float vals[1024];
    __shared__ int selidx[KTOP];
    __shared__ float sp[KTOP * 97];
    __shared__ float y1[16 * 30];
    __shared__ float pool[16 * 15];
    __shared__ float y2[352];
    int b = blockIdx.x, tid = threadIdx.x;
    const float* fb = feat + (size_t)b * NPG_ * 97;
    for (int u = tid; u < NPG_; u += 256) vals[u] = fb[(size_t)u * 97 + 96];
    __syncthreads();
    // single-wave register tournament: max value, tie -> lowest index (JAX top_k order)
    if (tid < 64) {
        unsigned long long keys[16];
        #pragma unroll
        for (int r = 0; r < 16; ++r) {
            int u = tid * 16 + r;
            unsigned int bb = __float_as_uint(vals[u]);
            unsigned int ord = (bb & 0x80000000u) ? ~bb : (bb | 0x80000000u);
            keys[r] = ((unsigned long long)ord << 32) |
                      (unsigned long long)(0xFFFFFFFFu - (unsigned int)u);
        }
        for (int k = 0; k < KTOP; ++k) {
            unsigned long long m = keys[0];
            #pragma unroll
            for (int r = 1; r < 16; ++r) m = (keys[r] > m) ? keys[r] : m;
            #pragma unroll
            for (int o = 32; o; o >>= 1) {
                unsigned long long t = __shfl_xor(m, o);
                m = (t > m) ? t : m;
            }
            int u = (int)(0xFFFFFFFFu - (unsigned int)(m & 0xFFFFFFFFull));
            if (tid == 0) selidx[k] = u;
            #pragma unroll
            for (int r = 0; r < 16; ++r)
                if (tid * 16 + r == u) keys[r] = 0ull;
        }
    }
    __syncthreads();
    for (int idx = tid; idx < KTOP * 97; idx += 256) {
        int t = idx / 97, d = idx - t * 97;
        sp[idx] = fb[(size_t)selidx[t] * 97 + d];
    }
    __syncthreads();
    for (int idx = tid; idx < 480; idx += 256) {
        int t = idx >> 4, c = idx & 15;
        float acc = bc1[c];
        for (int d = 0; d < 97; ++d) acc += sp[t * 97 + d] * wc1[c * 97 + d];
        y1[c * 30 + t] = fmaxf(acc, 0.f);
    }
    __syncthreads();
    for (int idx = tid; idx < 240; idx += 256) {
        int c = idx / 15, u = idx - c * 15;
        pool[c * 15 + u] = fmaxf(y1[c * 30 + 2 * u], y1[c * 30 + 2 * u + 1]);
    }
    __syncthreads();
    for (int idx = tid; idx < 352; idx += 256) {
        int o = idx / 11, t = idx - o * 11;
        float acc = bc2[o];
        for (int i = 0; i < 16; ++i)
            for (int kk = 0; kk < 5; ++kk)
                acc += pool[i * 15 + t + kk] * wc2[(o * 16 + i) * 5 + kk];
        y2[idx] = fmaxf(acc, 0.f);
    }
    __syncthreads();
    if (tid < 2) {
        float acc = bout[tid];
        for (int m = 0; m < 352; ++m) acc += y2[m] * wout[m * 2 + tid];
        out[b * 2 + tid] = fmaxf(acc, 0.f);
    }
}

// ---------------- launch ----------------

extern "C" void kernel_launch(void* const* d_in, const int* in_sizes, int n_in,
                              void* d_out, int out_size, void* d_ws, size_t ws_size,
                              hipStream_t stream) {
    const float* node_feat = (const float*)d_in[0];
    const float* edge_feat = (const float*)d_in[1];
    const int*   eidx      = (const int*)d_in[2];
    const float* W0 = (const float*)d_in[3];
    const float* b0 = (const float*)d_in[4];
    const float* W1 = (const float*)d_in[5];
    const float* b1 = (const float*)d_in[6];
    const float* W2 = (const float*)d_in[7];
    const float* b2 = (const float*)d_in[8];
    const float* W3 = (const float*)d_in[9];
    const float* b3 = (const float*)d_in[10];
    const float* wc1 = (const float*)d_in[11];
    const float* bc1 = (const float*)d_in[12];
    const float* wc2 = (const float*)d_in[13];
    const float* bc2 = (const float*)d_in[14];
    const float* wout = (const float*)d_in[15];
    const float* bout = (const float*)d_in[16];
    float* out = (float*)d_out;

    const int* src = eidx;
    const int* dst = eidx + N_EDGES;

    char* ws = (char*)d_ws;
    size_t off = 0;
    auto alloc = [&](size_t bytes) -> char* {
        char* p = ws + off;
        off += (bytes + 255) & ~(size_t)255;
        return p;
    };
    int* cnt       = (int*)alloc((size_t)N_NODES * 4);
    int* row_start = (int*)alloc((size_t)N_NODES * 4);
    int* cursor    = (int*)alloc((size_t)N_NODES * 4);
    int* blocksum  = (int*)alloc(512 * 4);
    float* degf    = (float*)alloc((size_t)N_NODES * 4);
    int* csr_src   = (int*)alloc((size_t)N_EDGES * 4);
    int* csr_eid   = (int*)alloc((size_t)N_EDGES * 4);
    float* z0      = (float*)alloc((size_t)N_NODES * 32 * 4);
    float* z1      = (float*)alloc((size_t)N_NODES * 32 * 4);
    float* z2      = (float*)alloc((size_t)N_NODES * 32 * 4);
    float* z3      = (float*)alloc((size_t)N_NODES * 4);
    float* feat    = (float*)alloc((size_t)N_NODES * 97 * 4);
    (void)ws_size;

    k_zero<<<N_NODES / 256, 256, 0, stream>>>(cnt);
    k_count<<<N_EDGES / 256, 256, 0, stream>>>(dst, cnt);
    k_scan1<<<N_NODES / 256, 256, 0, stream>>>(cnt, row_start, blocksum);
    k_scan2<<<1, 512, 0, stream>>>(blocksum);
    k_scan3<<<N_NODES / 256, 256, 0, stream>>>(row_start, blocksum, cursor);
    k_fill<<<N_EDGES / 256, 256, 0, stream>>>(src, dst, cursor, csr_src, csr_eid);
    k_z<<<N_NODES / 8, 256, 0, stream>>>(node_feat, edge_feat, W0, row_start, cnt, csr_eid, z0, degf);
    k_gather<<<N_NODES / 8, 256, 0, stream>>>(z0, row_start, cnt, csr_src, b0, degf, W1, feat, 0, z1);
    k_gather<<<N_NODES / 8, 256, 0, stream>>>(z1, row_start, cnt, csr_src, b1, degf, W2, feat, 32, z2);
    k_gather2<<<N_NODES / 8, 256, 0, stream>>>(z2, row_start, cnt, csr_src, b2, degf, W3, feat, z3);
    k_gather3<<<N_NODES / 256, 256, 0, stream>>>(z3, row_start, cnt, csr_src, b3, degf, feat);
    k_head<<<B_GR, 256, 0, stream>>>(feat, wc1, bc1, wc2, bc2, wout, bout, out);
}

// Round 4
// 671.133 us; speedup vs baseline: 1.4980x; 1.1003x over previous
//
#include <hip/hip_runtime.h>
#include <hip/hip_bf16.h>
#include <math.h>

#define N_NODES 131072
#define N_EDGES 1048576
#define B_GR    128
#define NPG_    1024
#define KTOP    30

// ---------------- CSR build ----------------

__global__ __launch_bounds__(256) void k_zero(int* cnt) {
    int i = blockIdx.x * 256 + threadIdx.x;
    if (i < N_NODES) cnt[i] = 0;
}

__global__ __launch_bounds__(256) void k_count(const int* __restrict__ dst, int* __restrict__ cnt) {
    int e = blockIdx.x * 256 + threadIdx.x;
    if (e < N_EDGES) atomicAdd(&cnt[dst[e]], 1);
}

__global__ __launch_bounds__(256) void k_scan1(const int* __restrict__ cnt,
                                               int* __restrict__ row_start,
                                               int* __restrict__ blocksum) {
    __shared__ int s[256];
    int t = threadIdx.x;
    int i = blockIdx.x * 256 + t;
    int v = cnt[i];
    s[t] = v; __syncthreads();
    for (int o = 1; o < 256; o <<= 1) {
        int x = (t >= o) ? s[t - o] : 0;
        __syncthreads();
        s[t] += x;
        __syncthreads();
    }
    row_start[i] = s[t] - v;
    if (t == 255) blocksum[blockIdx.x] = s[t];
}

__global__ __launch_bounds__(512) void k_scan2(int* __restrict__ blocksum) {
    __shared__ int s[512];
    int t = threadIdx.x;
    int v = blocksum[t];
    s[t] = v; __syncthreads();
    for (int o = 1; o < 512; o <<= 1) {
        int x = (t >= o) ? s[t - o] : 0;
        __syncthreads();
        s[t] += x;
        __syncthreads();
    }
    blocksum[t] = s[t] - v;
}

__global__ __launch_bounds__(256) void k_scan3(int* __restrict__ row_start,
                                               const int* __restrict__ blocksum,
                                               int* __restrict__ cursor) {
    int i = blockIdx.x * 256 + threadIdx.x;
    int r = row_start[i] + blocksum[blockIdx.x];
    row_start[i] = r;
    cursor[i] = r;
}

// csr[pos] = (src, eid) packed — one 8-B scatter instead of two 4-B
__global__ __launch_bounds__(256) void k_fill(const int* __restrict__ src,
                                              const int* __restrict__ dst,
                                              int* __restrict__ cursor,
                                              int2* __restrict__ csr) {
    int e = blockIdx.x * 256 + threadIdx.x;
    if (e < N_EDGES) {
        int d = dst[e];
        int pos = atomicAdd(&cursor[d], 1);
        csr[pos] = make_int2(src[e], e);
    }
}

// ---------------- esum[n][32] = sum of incident edge_feat rows (pure gather)

__global__ __launch_bounds__(256) void k_esum(const float* __restrict__ ef,
                                              const int* __restrict__ row_start,
                                              const int* __restrict__ cnt,
                                              const int2* __restrict__ csr,
                                              float* __restrict__ esum) {
    int g = threadIdx.x >> 5, j = threadIdx.x & 31;
    int n = blockIdx.x * 8 + g;
    int start = row_start[n], len = cnt[n];
    const int2* ce = csr + start;
    float s = 0.f;
    int i = 0;
    for (; i + 8 <= len; i += 8) {
        int e0 = ce[i].y, e1 = ce[i + 1].y, e2 = ce[i + 2].y, e3 = ce[i + 3].y;
        int e4 = ce[i + 4].y, e5 = ce[i + 5].y, e6 = ce[i + 6].y, e7 = ce[i + 7].y;
        float a0 = ef[(size_t)e0 * 32 + j], a1 = ef[(size_t)e1 * 32 + j];
        float a2 = ef[(size_t)e2 * 32 + j], a3 = ef[(size_t)e3 * 32 + j];
        float a4 = ef[(size_t)e4 * 32 + j], a5 = ef[(size_t)e5 * 32 + j];
        float a6 = ef[(size_t)e6 * 32 + j], a7 = ef[(size_t)e7 * 32 + j];
        s += ((a0 + a1) + (a2 + a3)) + ((a4 + a5) + (a6 + a7));
    }
    for (; i < len; ++i) s += ef[(size_t)ce[i].y * 32 + j];
    esum[(size_t)n * 32 + j] = s;
}

// ---------------- z0 = [nf | esum] @ W0   (K=160, SGPR weights, lane=node)

__global__ __launch_bounds__(256) void k_gemm160(const float* __restrict__ nf,
                                                 const float* __restrict__ esum,
                                                 const float* __restrict__ W0,
                                                 float* __restrict__ z0) {
    __shared__ float a[64 * 161];
    int tid = threadIdx.x;
    int n0 = blockIdx.x * 64;
    // stage nf tile (64 x 128, contiguous 32 KB) and esum tile (64 x 32)
    const float* nfb = nf + (size_t)n0 * 128;
    for (int f = tid; f < 8192; f += 256) {
        int n = f >> 7, k = f & 127;
        a[n * 161 + k] = nfb[f];
    }
    const float* esb = esum + (size_t)n0 * 32;
    for (int f = tid; f < 2048; f += 256) {
        int n = f >> 5, k = f & 31;
        a[n * 161 + 128 + k] = esb[f];
    }
    __syncthreads();
    int wv = __builtin_amdgcn_readfirstlane(tid >> 6);   // wave id -> col group (uniform)
    int lane = tid & 63;                                  // node within tile
    int c0 = wv * 8;
    float acc[8] = {0.f, 0.f, 0.f, 0.f, 0.f, 0.f, 0.f, 0.f};
    const float* ar = a + lane * 161;
    for (int k = 0; k < 160; ++k) {
        float av = ar[k];
        #pragma unroll
        for (int jj = 0; jj < 8; ++jj)
            acc[jj] += av * W0[k * 32 + c0 + jj];          // uniform addr -> s_load
    }
    float* zr = z0 + (size_t)(n0 + lane) * 32 + c0;
    *(float4*)zr = make_float4(acc[0], acc[1], acc[2], acc[3]);
    *(float4*)(zr + 4) = make_float4(acc[4], acc[5], acc[6], acc[7]);
}

// ---------------- z_next = h @ W  (K=32, same scheme)

__global__ __launch_bounds__(256) void k_gemm32(const float* __restrict__ h,
                                                const float* __restrict__ W,
                                                float* __restrict__ zout) {
    __shared__ float a[64 * 33];
    int tid = threadIdx.x;
    int n0 = blockIdx.x * 64;
    const float* hb = h + (size_t)n0 * 32;
    for (int f = tid; f < 2048; f += 256) {
        int n = f >> 5, k = f & 31;
        a[n * 33 + k] = hb[f];
    }
    __syncthreads();
    int wv = __builtin_amdgcn_readfirstlane(tid >> 6);
    int lane = tid & 63;
    int c0 = wv * 8;
    float acc[8] = {0.f, 0.f, 0.f, 0.f, 0.f, 0.f, 0.f, 0.f};
    const float* ar = a + lane * 33;
    #pragma unroll
    for (int k = 0; k < 32; ++k) {
        float av = ar[k];
        #pragma unroll
        for (int jj = 0; jj < 8; ++jj)
            acc[jj] += av * W[k * 32 + c0 + jj];
    }
    float* zr = zout + (size_t)(n0 + lane) * 32 + c0;
    *(float4*)zr = make_float4(acc[0], acc[1], acc[2], acc[3]);
    *(float4*)(zr + 4) = make_float4(acc[4], acc[5], acc[6], acc[7]);
}

// ---------------- gather layer: h = tanh((z_self + sum z_nb + b)/deg)

__global__ __launch_bounds__(256) void k_g(const float* __restrict__ zin,
                                           const int* __restrict__ row_start,
                                           const int* __restrict__ cnt,
                                           const int2* __restrict__ csr,
                                           const float* __restrict__ bias,
                                           float* __restrict__ hout) {
    int g = threadIdx.x >> 5, j = threadIdx.x & 31;
    int n = blockIdx.x * 8 + g;
    int start = row_start[n], len = cnt[n];
    const int2* cs = csr + start;
    float p = zin[(size_t)n * 32 + j];
    int i = 0;
    for (; i + 8 <= len; i += 8) {
        int s0 = cs[i].x, s1 = cs[i + 1].x, s2 = cs[i + 2].x, s3 = cs[i + 3].x;
        int s4 = cs[i + 4].x, s5 = cs[i + 5].x, s6 = cs[i + 6].x, s7 = cs[i + 7].x;
        float a0 = zin[(size_t)s0 * 32 + j], a1 = zin[(size_t)s1 * 32 + j];
        float a2 = zin[(size_t)s2 * 32 + j], a3 = zin[(size_t)s3 * 32 + j];
        float a4 = zin[(size_t)s4 * 32 + j], a5 = zin[(size_t)s5 * 32 + j];
        float a6 = zin[(size_t)s6 * 32 + j], a7 = zin[(size_t)s7 * 32 + j];
        p += ((a0 + a1) + (a2 + a3)) + ((a4 + a5) + (a6 + a7));
    }
    for (; i < len; ++i) p += zin[(size_t)cs[i].x * 32 + j];
    float deg = 1.f + (float)len;
    hout[(size_t)n * 32 + j] = tanhf((p + bias[j]) / deg);
}

// ---------------- last 32-wide layer: h2 + premultiplied scalar z3 = h2 @ W3

__global__ __launch_bounds__(256) void k_g2(const float* __restrict__ zin,
                                            const int* __restrict__ row_start,
                                            const int* __restrict__ cnt,
                                            const int2* __restrict__ csr,
                                            const float* __restrict__ bias,
                                            const float* __restrict__ W3,
                                            float* __restrict__ hout,
                                            float* __restrict__ z3) {
    int g = threadIdx.x >> 5, j = threadIdx.x & 31;
    int n = blockIdx.x * 8 + g;
    int start = row_start[n], len = cnt[n];
    const int2* cs = csr + start;
    float p = zin[(size_t)n * 32 + j];
    int i = 0;
    for (; i + 8 <= len; i += 8) {
        int s0 = cs[i].x, s1 = cs[i + 1].x, s2 = cs[i + 2].x, s3 = cs[i + 3].x;
        int s4 = cs[i + 4].x, s5 = cs[i + 5].x, s6 = cs[i + 6].x, s7 = cs[i + 7].x;
        float a0 = zin[(size_t)s0 * 32 + j], a1 = zin[(size_t)s1 * 32 + j];
        float a2 = zin[(size_t)s2 * 32 + j], a3 = zin[(size_t)s3 * 32 + j];
        float a4 = zin[(size_t)s4 * 32 + j], a5 = zin[(size_t)s5 * 32 + j];
        float a6 = zin[(size_t)s6 * 32 + j], a7 = zin[(size_t)s7 * 32 + j];
        p += ((a0 + a1) + (a2 + a3)) + ((a4 + a5) + (a6 + a7));
    }
    for (; i < len; ++i) p += zin[(size_t)cs[i].x * 32 + j];
    float deg = 1.f + (float)len;
    float h = tanhf((p + bias[j]) / deg);
    hout[(size_t)n * 32 + j] = h;
    float t = h * W3[j];
    #pragma unroll
    for (int o = 16; o; o >>= 1) t += __shfl_xor(t, o, 32);
    if (j == 0) z3[n] = t;
}

// ---------------- layer 3: scalar gather-sum -> val

__global__ __launch_bounds__(256) void k_g3(const float* __restrict__ z3,
                                            const int* __restrict__ row_start,
                                            const int* __restrict__ cnt,
                                            const int2* __restrict__ csr,
                                            const float* __restrict__ b3,
                                            float* __restrict__ val) {
    int n = blockIdx.x * 256 + threadIdx.x;
    int start = row_start[n], len = cnt[n];
    const int2* cs = csr + start;
    float s = z3[n];
    int i = 0;
    for (; i + 4 <= len; i += 4)
        s += z3[cs[i].x] + z3[cs[i + 1].x] + z3[cs[i + 2].x] + z3[cs[i + 3].x];
    for (; i < len; ++i) s += z3[cs[i].x];
    float deg = 1.f + (float)len;
    val[n] = tanhf((s + b3[0]) / deg);
}

// ---------------- top-k + conv head, one block per graph ----------------

__global__ __launch_bounds__(256) void k_head(const float* __restrict__ h0,
                                              const float* __restrict__ h1,
                                              const float* __restrict__ h2,
                                              const float* __restrict__ val,
                                              const float* __restrict__ wc1,
                                              const float* __restrict__ bc1,
                                              const float* __restrict__ wc2,
                                              const float* __restrict__ bc2,
                                              const float* __restrict__ wout,
                                              const float* __restrict__ bout,
                                              float* __restrict__ out) {
    __shared__ float vals[1024];
    __shared__ int selidx[KTOP];
    __shared__ float sp[KTOP * 97];
    __shared__ float y1[16 * 30];
    __shared__ float pool[16 * 15];
    __shared__ float y2[352];
    int b = blockIdx.x, tid = threadIdx.x;
    const float* vb = val + (size_t)b * NPG_;
    for (int u = tid; u < NPG_; u += 256) vals[u] = vb[u];
    __syncthreads();
    // single-wave register tournament: max value, tie -> lowest index (JAX top_k order)
    if (tid < 64) {
        unsigned long long keys[16];
        #pragma unroll
        for (int r = 0; r < 16; ++r) {
            int u = tid * 16 + r;
            unsigned int bb = __float_as_uint(vals[u]);
            unsigned int ord = (bb & 0x80000000u) ? ~bb : (bb | 0x80000000u);
            keys[r] = ((unsigned long long)ord << 32) |
                      (unsigned long long)(0xFFFFFFFFu - (unsigned int)u);
        }
        for (int k = 0; k < KTOP; ++k) {
            unsigned long long m = keys[0];
            #pragma unroll
            for (int r = 1; r < 16; ++r) m = (keys[r] > m) ? keys[r] : m;
            #pragma unroll
            for (int o = 32; o; o >>= 1) {
                unsigned long long t = __shfl_xor(m, o);
                m = (t > m) ? t : m;
            }
            int u = (int)(0xFFFFFFFFu - (unsigned int)(m & 0xFFFFFFFFull));
            if (tid == 0) selidx[k] = u;
            #pragma unroll
            for (int r = 0; r < 16; ++r)
                if (tid * 16 + r == u) keys[r] = 0ull;
        }
    }
    __syncthreads();
    size_t nb = (size_t)b * NPG_;
    for (int idx = tid; idx < KTOP * 32; idx += 256) {
        int t = idx >> 5, d = idx & 31;
        size_t s = (nb + (size_t)selidx[t]) * 32;
        sp[t * 97 + d]      = h0[s + d];
        sp[t * 97 + 32 + d] = h1[s + d];
        sp[t * 97 + 64 + d] = h2[s + d];
    }
    if (tid < KTOP) sp[tid * 97 + 96] = vb[selidx[tid]];
    __syncthreads();
    for (int idx = tid; idx < 480; idx += 256) {
        int t = idx >> 4, c = idx & 15;
        float acc = bc1[c];
        for (int d = 0; d < 97; ++d) acc += sp[t * 97 + d] * wc1[c * 97 + d];
        y1[c * 30 + t] = fmaxf(acc, 0.f);
    }
    __syncthreads();
    for (int idx = tid; idx < 240; idx += 256) {
        int c = idx / 15, u = idx - c * 15;
        pool[c * 15 + u] = fmaxf(y1[c * 30 + 2 * u], y1[c * 30 + 2 * u + 1]);
    }
    __syncthreads();
    for (int idx = tid; idx < 352; idx += 256) {
        int o = idx / 11, t = idx - o * 11;
        float acc = bc2[o];
        for (int i = 0; i < 16; ++i)
            for (int kk = 0; kk < 5; ++kk)
                acc += pool[i * 15 + t + kk] * wc2[(o * 16 + i) * 5 + kk];
        y2[idx] = fmaxf(acc, 0.f);
    }
    __syncthreads();
    if (tid < 2) {
        float acc = bout[tid];
        for (int m = 0; m < 352; ++m) acc += y2[m] * wout[m * 2 + tid];
        out[b * 2 + tid] = fmaxf(acc, 0.f);
    }
}

// ---------------- launch ----------------

extern "C" void kernel_launch(void* const* d_in, const int* in_sizes, int n_in,
                              void* d_out, int out_size, void* d_ws, size_t ws_size,
                              hipStream_t stream) {
    const float* node_feat = (const float*)d_in[0];
    const float* edge_feat = (const float*)d_in[1];
    const int*   eidx      = (const int*)d_in[2];
    const float* W0 = (const float*)d_in[3];
    const float* b0 = (const float*)d_in[4];
    const float* W1 = (const float*)d_in[5];
    const float* b1 = (const float*)d_in[6];
    const float* W2 = (const float*)d_in[7];
    const float* b2 = (const float*)d_in[8];
    const float* W3 = (const float*)d_in[9];
    const float* b3 = (const float*)d_in[10];
    const float* wc1 = (const float*)d_in[11];
    const float* bc1 = (const float*)d_in[12];
    const float* wc2 = (const float*)d_in[13];
    const float* bc2 = (const float*)d_in[14];
    const float* wout = (const float*)d_in[15];
    const float* bout = (const float*)d_in[16];
    float* out = (float*)d_out;

    const int* src = eidx;
    const int* dst = eidx + N_EDGES;

    char* ws = (char*)d_ws;
    size_t off = 0;
    auto alloc = [&](size_t bytes) -> char* {
        char* p = ws + off;
        off += (bytes + 255) & ~(size_t)255;
        return p;
    };
    int* cnt       = (int*)alloc((size_t)N_NODES * 4);
    int* row_start = (int*)alloc((size_t)N_NODES * 4);
    int* cursor    = (int*)alloc((size_t)N_NODES * 4);
    int* blocksum  = (int*)alloc(512 * 4);
    int2* csr      = (int2*)alloc((size_t)N_EDGES * 8);
    float* esum    = (float*)alloc((size_t)N_NODES * 32 * 4);
    float* z0      = (float*)alloc((size_t)N_NODES * 32 * 4);
    float* z1      = (float*)alloc((size_t)N_NODES * 32 * 4);
    float* z2      = (float*)alloc((size_t)N_NODES * 32 * 4);
    float* h0      = (float*)alloc((size_t)N_NODES * 32 * 4);
    float* h1      = (float*)alloc((size_t)N_NODES * 32 * 4);
    float* h2      = (float*)alloc((size_t)N_NODES * 32 * 4);
    float* z3      = (float*)alloc((size_t)N_NODES * 4);
    float* val     = (float*)alloc((size_t)N_NODES * 4);
    (void)ws_size;

    k_zero<<<N_NODES / 256, 256, 0, stream>>>(cnt);
    k_count<<<N_EDGES / 256, 256, 0, stream>>>(dst, cnt);
    k_scan1<<<N_NODES / 256, 256, 0, stream>>>(cnt, row_start, blocksum);
    k_scan2<<<1, 512, 0, stream>>>(blocksum);
    k_scan3<<<N_NODES / 256, 256, 0, stream>>>(row_start, blocksum, cursor);
    k_fill<<<N_EDGES / 256, 256, 0, stream>>>(src, dst, cursor, csr);
    k_esum<<<N_NODES / 8, 256, 0, stream>>>(edge_feat, row_start, cnt, csr, esum);
    k_gemm160<<<N_NODES / 64, 256, 0, stream>>>(node_feat, esum, W0, z0);
    k_g<<<N_NODES / 8, 256, 0, stream>>>(z0, row_start, cnt, csr, b0, h0);
    k_gemm32<<<N_NODES / 64, 256, 0, stream>>>(h0, W1, z1);
    k_g<<<N_NODES / 8, 256, 0, stream>>>(z1, row_start, cnt, csr, b1, h1);
    k_gemm32<<<N_NODES / 64, 256, 0, stream>>>(h1, W2, z2);
    k_g2<<<N_NODES / 8, 256, 0, stream>>>(z2, row_start, cnt, csr, b2, W3, h2, z3);
    k_g3<<<N_NODES / 256, 256, 0, stream>>>(z3, row_start, cnt, csr, b3, val);
    k_head<<<B_GR, 256, 0, stream>>>(h0, h1, h2, val, wc1, bc1, wc2, bc2, wout, bout, out);
}